// Round 1
// baseline (367.766 us; speedup 1.0000x reference)
//
#include <hip/hip_runtime.h>
#include <math.h>

#define H_DIM 2880
#define E_NUM 32
#define TOPK 4
#define TT 256       // tokens per block (kernel B)
#define HCHUNK 360   // h elements per chunk
#define NCH 8        // number of h-chunks (HCHUNK*NCH == H_DIM)
#define KS 20        // k per LDS stage (float4-aligned, bank-conflict-free stride)
#define NS (HCHUNK / KS)  // 18 stages

// ---------------- Kernel A: transpose weight [E][H] -> wt[H][E] ----------------
__global__ void transpose_w(const float* __restrict__ w, float* __restrict__ wt) {
    __shared__ float tile[32][33];  // +1 pad: conflict-free
    const int h0 = blockIdx.x * 32;
    const int tx = threadIdx.x;  // 0..31
    const int ty = threadIdx.y;  // 0..31
    // coalesced read: expert ty, h = h0+tx
    tile[tx][ty] = w[ty * H_DIM + h0 + tx];
    __syncthreads();
    // coalesced write: wt[(h0+ty)*32 + tx] = w[tx][h0+ty] = tile[ty][tx]
    wt[(h0 + ty) * E_NUM + tx] = tile[ty][tx];
}

// ---------------- Kernel B: partial logits per h-chunk ----------------
// grid (T/TT, NCH), block 256. Thread = one token; acc[32] over its h-chunk.
// x staged coalesced via LDS (register-staged single-buffer pipeline);
// weight read via wave-uniform float4 loads from wt[k][e] (-> s_load via K$).
__global__ __launch_bounds__(256) void partial_logits(
    const float* __restrict__ x, const float* __restrict__ wt,
    float* __restrict__ part, int T) {
    __shared__ float xs[TT * KS];  // 20 KB, row-major [TT][KS]
    const int tid = threadIdx.x;
    const int t0 = blockIdx.x * TT;
    const int k0 = blockIdx.y * HCHUNK;

    // Each stage stages TT*KS floats = 1280 float4; 5 per thread.
    // slot f = i*256+tid -> token row r=f/5, col c=f%5 (col = float4 within row)
    const float* gsrc[5];
#pragma unroll
    for (int i = 0; i < 5; ++i) {
        int f = i * 256 + tid;
        int r = f / 5, c = f % 5;
        gsrc[i] = x + (size_t)(t0 + r) * H_DIM + k0 + c * 4;
    }

    // prologue: load stage 0 into registers
    float4 reg[5];
#pragma unroll
    for (int i = 0; i < 5; ++i) reg[i] = *(const float4*)(gsrc[i]);

    float acc[E_NUM];
#pragma unroll
    for (int e = 0; e < E_NUM; ++e) acc[e] = 0.0f;

    const float4* wt4 = (const float4*)wt;  // wt row (one k) = 8 float4

    for (int s = 0; s < NS; ++s) {
        __syncthreads();  // LDS free (everyone done computing stage s-1)
#pragma unroll
        for (int i = 0; i < 5; ++i)
            *(float4*)&xs[(i * 256 + tid) * 4] = reg[i];
        if (s + 1 < NS) {  // issue next stage's global loads NOW (overlap w/ compute)
#pragma unroll
            for (int i = 0; i < 5; ++i)
                reg[i] = *(const float4*)(gsrc[i] + (size_t)(s + 1) * KS);
        }
        __syncthreads();  // LDS populated

        const int kbase = k0 + s * KS;
#pragma unroll
        for (int kk = 0; kk < KS / 4; ++kk) {
            float4 xv = *(const float4*)&xs[tid * KS + kk * 4];
#pragma unroll
            for (int c = 0; c < 4; ++c) {
                float xk = (&xv.x)[c];
                int kg = kbase + kk * 4 + c;  // wave-uniform
#pragma unroll
                for (int j = 0; j < 8; ++j) {
                    float4 w4 = wt4[kg * 8 + j];  // uniform -> s_load through K$
                    acc[j * 4 + 0] += xk * w4.x;
                    acc[j * 4 + 1] += xk * w4.y;
                    acc[j * 4 + 2] += xk * w4.z;
                    acc[j * 4 + 3] += xk * w4.w;
                }
            }
        }
    }

    // part[hc][t][e], 128 B contiguous per thread -> coalesced wave stores
    float4* out4 = (float4*)(part + ((size_t)blockIdx.y * T + t0 + tid) * E_NUM);
#pragma unroll
    for (int j = 0; j < 8; ++j)
        out4[j] = make_float4(acc[j * 4 + 0], acc[j * 4 + 1], acc[j * 4 + 2], acc[j * 4 + 3]);
}

// ---------------- Kernel C: reduce chunks + bias, top-4, softmax ----------------
__global__ void topk_softmax(const float* __restrict__ part,
                             const float* __restrict__ bias,
                             float* __restrict__ out, int T) {
    const int t = blockIdx.x * 64 + threadIdx.x;
    if (t >= T) return;

    float logit[E_NUM];
    const float4* b4 = (const float4*)bias;
#pragma unroll
    for (int j = 0; j < 8; ++j) {
        float4 b = b4[j];
        logit[j * 4 + 0] = b.x; logit[j * 4 + 1] = b.y;
        logit[j * 4 + 2] = b.z; logit[j * 4 + 3] = b.w;
    }
    for (int hc = 0; hc < NCH; ++hc) {
        const float4* p4 = (const float4*)(part + ((size_t)hc * T + t) * E_NUM);
#pragma unroll
        for (int j = 0; j < 8; ++j) {
            float4 p = p4[j];
            logit[j * 4 + 0] += p.x; logit[j * 4 + 1] += p.y;
            logit[j * 4 + 2] += p.z; logit[j * 4 + 3] += p.w;
        }
    }

    // top-4, descending, ties -> lowest index (strict >, ascending scan)
    int idx[TOPK];
    float val[TOPK];
#pragma unroll
    for (int k = 0; k < TOPK; ++k) {
        float best = -INFINITY;
        int bi = 0;
#pragma unroll
        for (int e = 0; e < E_NUM; ++e) {
            bool taken = false;
            for (int p = 0; p < k; ++p) taken = taken || (idx[p] == e);
            float v = logit[e];
            if (!taken && v > best) { best = v; bi = e; }
        }
        idx[k] = bi;
        val[k] = best;
    }

    // softmax over the 4 (val[0] is the max)
    float ex[TOPK], sum = 0.0f;
#pragma unroll
    for (int k = 0; k < TOPK; ++k) { ex[k] = expf(val[k] - val[0]); sum += ex[k]; }
    float inv = 1.0f / sum;

    // output: [T*4 indices as float] then [T*4 weights]
#pragma unroll
    for (int k = 0; k < TOPK; ++k) {
        out[(size_t)t * 4 + k] = (float)idx[k];
        out[(size_t)T * 4 + (size_t)t * 4 + k] = ex[k] * inv;
    }
}

extern "C" void kernel_launch(void* const* d_in, const int* in_sizes, int n_in,
                              void* d_out, int out_size, void* d_ws, size_t ws_size,
                              hipStream_t stream) {
    const float* x    = (const float*)d_in[0];  // [B,S,H] fp32
    const float* w    = (const float*)d_in[1];  // [E,H] fp32
    const float* bias = (const float*)d_in[2];  // [E] fp32
    float* out = (float*)d_out;

    const int T = in_sizes[0] / H_DIM;  // 16384

    // workspace layout: partials [NCH][T][E] fp32, then wt [H][E] fp32
    float* part = (float*)d_ws;
    float* wt = part + (size_t)NCH * T * E_NUM;

    transpose_w<<<dim3(H_DIM / 32), dim3(32, 32), 0, stream>>>(w, wt);
    partial_logits<<<dim3(T / TT, NCH), 256, 0, stream>>>(x, wt, part, T);
    topk_softmax<<<dim3((T + 63) / 64), 64, 0, stream>>>(part, bias, out, T);
}

// Round 2
// 318.792 us; speedup vs baseline: 1.1536x; 1.1536x over previous
//
#include <hip/hip_runtime.h>
#include <math.h>

#define H_DIM 2880
#define E_NUM 32
#define TOPK 4
#define TT 256       // tokens per block (kernel B) == block size (1 token/thread)
#define HCHUNK 360   // h elements per chunk
#define NCH 8        // number of h-chunks (HCHUNK*NCH == H_DIM)
#define KS 20        // k per LDS stage (float4-aligned, conflict-free ds_read stride)
#define NS (HCHUNK / KS)  // 18 stages

// async global->LDS DMA, 16B per lane. LDS dest = wave-uniform base + lane*16
// (rigid); global side is a per-lane address (flexible). No VGPR round-trip.
#define GLD16(gp, lp)                                                  \
    __builtin_amdgcn_global_load_lds(                                  \
        (const __attribute__((address_space(1))) void*)(gp),           \
        (__attribute__((address_space(3))) void*)(lp), 16, 0, 0)

// ---------------- Kernel A: transpose weight [E][H] -> wt[H][E] ----------------
__global__ void transpose_w(const float* __restrict__ w, float* __restrict__ wt) {
    __shared__ float tile[32][33];
    const int h0 = blockIdx.x * 32;
    const int tx = threadIdx.x;
    const int ty = threadIdx.y;
    tile[tx][ty] = w[ty * H_DIM + h0 + tx];
    __syncthreads();
    wt[(h0 + ty) * E_NUM + tx] = tile[ty][tx];
}

// ---------------- Kernel B: partial logits per h-chunk ----------------
// grid (T/TT, NCH), block 256. Thread = one token; acc[32] fp32 in VGPRs.
// x staged via double-buffered async global_load_lds DMA (no staging VGPRs ->
// no spill; R1's VGPR_Count=40 + 183MB scratch writebacks are eliminated).
// Weights read wave-uniform -> s_load through K$ (SGPR_Count=112 in R1 confirms).
__global__ __launch_bounds__(256, 2) void partial_logits(
    const float* __restrict__ x, const float* __restrict__ wt,
    float* __restrict__ part, int T) {
    __shared__ float xs[2][TT * KS];  // 2 x 20 KB
    const int tid = threadIdx.x;
    const int t0 = blockIdx.x * TT;
    const int k0 = blockIdx.y * HCHUNK;
    const int wave = tid >> 6, lane = tid & 63;

    // Each stage = TT*KS floats = 1280 float4 slots; 5 DMA instrs per wave.
    // Slot f lives at LDS float-offset f*4 and sources token r=f/5, col c=f%5.
    const float* g[5];
    int ldsoff[5];
#pragma unroll
    for (int i = 0; i < 5; ++i) {
        int f = wave * 320 + i * 64 + lane;
        int r = f / 5, c = f % 5;
        g[i] = x + (size_t)(t0 + r) * H_DIM + k0 + c * 4;
        ldsoff[i] = f * 4;
    }

    float acc[E_NUM];
#pragma unroll
    for (int e = 0; e < E_NUM; ++e) acc[e] = 0.0f;

    const float4* wt4 = (const float4*)wt;

    // prologue: stage 0 -> buf 0 (drained by first barrier)
#pragma unroll
    for (int i = 0; i < 5; ++i) GLD16(g[i], &xs[0][ldsoff[i]]);

    for (int s = 0; s < NS; ++s) {
        // Barrier drains this wave's outstanding DMA (vmcnt(0)) and syncs the
        // block: buf[s&1] is fully populated, and every wave has finished
        // reading buf[(s+1)&1] (its stage s-1 compute) -> safe to overwrite.
        __syncthreads();
        if (s + 1 < NS) {  // fire next stage's DMA; lands during compute(s)
#pragma unroll
            for (int i = 0; i < 5; ++i)
                GLD16(g[i] + (size_t)(s + 1) * KS, &xs[(s + 1) & 1][ldsoff[i]]);
        }

        const float* xrow = &xs[s & 1][tid * KS];
        const int kbase = k0 + s * KS;
#pragma unroll
        for (int kk = 0; kk < KS / 4; ++kk) {
            float4 xv = *(const float4*)&xrow[kk * 4];  // stride 20 dw: conflict-free
#pragma unroll
            for (int c = 0; c < 4; ++c) {
                float xk = (&xv.x)[c];
                int kg = kbase + kk * 4 + c;  // wave-uniform -> scalar loads
#pragma unroll
                for (int j = 0; j < 8; ++j) {
                    float4 w4 = wt4[kg * 8 + j];
                    acc[j * 4 + 0] += xk * w4.x;
                    acc[j * 4 + 1] += xk * w4.y;
                    acc[j * 4 + 2] += xk * w4.z;
                    acc[j * 4 + 3] += xk * w4.w;
                }
            }
        }
    }

    float4* out4 = (float4*)(part + ((size_t)blockIdx.y * T + t0 + tid) * E_NUM);
#pragma unroll
    for (int j = 0; j < 8; ++j)
        out4[j] = make_float4(acc[j * 4 + 0], acc[j * 4 + 1], acc[j * 4 + 2], acc[j * 4 + 3]);
}

// ---------------- Kernel C: reduce chunks + bias, top-4, softmax ----------------
__global__ void topk_softmax(const float* __restrict__ part,
                             const float* __restrict__ bias,
                             float* __restrict__ out, int T) {
    const int t = blockIdx.x * 64 + threadIdx.x;
    if (t >= T) return;

    float logit[E_NUM];
    const float4* b4 = (const float4*)bias;
#pragma unroll
    for (int j = 0; j < 8; ++j) {
        float4 b = b4[j];
        logit[j * 4 + 0] = b.x; logit[j * 4 + 1] = b.y;
        logit[j * 4 + 2] = b.z; logit[j * 4 + 3] = b.w;
    }
    for (int hc = 0; hc < NCH; ++hc) {
        const float4* p4 = (const float4*)(part + ((size_t)hc * T + t) * E_NUM);
#pragma unroll
        for (int j = 0; j < 8; ++j) {
            float4 p = p4[j];
            logit[j * 4 + 0] += p.x; logit[j * 4 + 1] += p.y;
            logit[j * 4 + 2] += p.z; logit[j * 4 + 3] += p.w;
        }
    }

    // top-4 descending, ties -> lowest index (strict >, ascending scan)
    int idx[TOPK];
    float val[TOPK];
#pragma unroll
    for (int k = 0; k < TOPK; ++k) {
        float best = -INFINITY;
        int bi = 0;
#pragma unroll
        for (int e = 0; e < E_NUM; ++e) {
            bool taken = false;
            for (int p = 0; p < k; ++p) taken = taken || (idx[p] == e);
            float v = logit[e];
            if (!taken && v > best) { best = v; bi = e; }
        }
        idx[k] = bi;
        val[k] = best;
    }

    float ex[TOPK], sum = 0.0f;
#pragma unroll
    for (int k = 0; k < TOPK; ++k) { ex[k] = expf(val[k] - val[0]); sum += ex[k]; }
    float inv = 1.0f / sum;

#pragma unroll
    for (int k = 0; k < TOPK; ++k) {
        out[(size_t)t * 4 + k] = (float)idx[k];
        out[(size_t)T * 4 + (size_t)t * 4 + k] = ex[k] * inv;
    }
}

extern "C" void kernel_launch(void* const* d_in, const int* in_sizes, int n_in,
                              void* d_out, int out_size, void* d_ws, size_t ws_size,
                              hipStream_t stream) {
    const float* x    = (const float*)d_in[0];  // [B,S,H] fp32
    const float* w    = (const float*)d_in[1];  // [E,H] fp32
    const float* bias = (const float*)d_in[2];  // [E] fp32
    float* out = (float*)d_out;

    const int T = in_sizes[0] / H_DIM;  // 16384

    float* part = (float*)d_ws;                       // [NCH][T][E]
    float* wt = part + (size_t)NCH * T * E_NUM;       // [H][E]

    transpose_w<<<dim3(H_DIM / 32), dim3(32, 32), 0, stream>>>(w, wt);
    partial_logits<<<dim3(T / TT, NCH), 256, 0, stream>>>(x, wt, part, T);
    topk_softmax<<<dim3((T + 63) / 64), 64, 0, stream>>>(part, bias, out, T);
}

// Round 3
// 307.164 us; speedup vs baseline: 1.1973x; 1.0379x over previous
//
#include <hip/hip_runtime.h>
#include <math.h>

#define H_DIM 2880
#define E_NUM 32
#define TOPK 4
#define NCH 16           // h-chunks
#define HCHUNK 180       // H_DIM / NCH
#define TB 512           // tokens per block (2 per thread)
#define KS 12            // k per LDS stage
#define NS 15            // HCHUNK / KS

typedef float vf16 __attribute__((ext_vector_type(16)));

// async global->LDS DMA, 16B/lane; LDS dest = wave-uniform base + lane*16.
#define GLD16(gp, lp)                                                  \
    __builtin_amdgcn_global_load_lds(                                  \
        (const __attribute__((address_space(1))) void*)(gp),           \
        (__attribute__((address_space(3))) void*)(lp), 16, 0, 0)

// ---------------- Kernel A: transpose weight [E][H] -> wt[H][E] ----------------
__global__ void transpose_w(const float* __restrict__ w, float* __restrict__ wt) {
    __shared__ float tile[32][33];
    const int h0 = blockIdx.x * 32;
    const int tx = threadIdx.x;
    const int ty = threadIdx.y;
    tile[tx][ty] = w[ty * H_DIM + h0 + tx];
    __syncthreads();
    wt[(h0 + ty) * E_NUM + tx] = tile[ty][tx];
}

// ---------------- Kernel B: partial logits per h-chunk ----------------
// grid (T/TB, NCH), block 256. Thread = 2 tokens (tid, tid+256) x 32 experts.
// M=2 halves scalar-load pressure per fmac; weights read as 2x s_load_dwordx16
// per k (wave-uniform vf16 loads). x via double-buffered global_load_lds DMA.
__global__ __launch_bounds__(256, 2) void partial_logits(
    const float* __restrict__ x, const float* __restrict__ wt,
    float* __restrict__ part, int T) {
    __shared__ float xs[2][TB * KS];  // 2 x 24 KB
    const int tid = threadIdx.x;
    const int t0 = blockIdx.x * TB;
    const int k0 = blockIdx.y * HCHUNK;
    const int wave = tid >> 6, lane = tid & 63;

    // stage = TB*KS floats = 1536 float4 slots; 6 DMA per lane.
    // slot f -> token row r=f/3, col c=f%3 (float4 within row's 12-float window)
    const float* g[6];
    int lo[6];
#pragma unroll
    for (int i = 0; i < 6; ++i) {
        int f = wave * 384 + i * 64 + lane;   // wave's slots contiguous, lane-ordered
        int r = f / 3, c = f % 3;
        g[i] = x + (size_t)(t0 + r) * H_DIM + k0 + c * 4;
        lo[i] = f * 4;
    }

    float acc[64];  // [0:32)=token a, [32:64)=token b
#pragma unroll
    for (int e = 0; e < 64; ++e) acc[e] = 0.f;

    const vf16* wtv = (const vf16*)wt;  // one k-row of wt = 2 x vf16 (128 B)

#pragma unroll
    for (int i = 0; i < 6; ++i) GLD16(g[i], &xs[0][lo[i]]);

    for (int s = 0; s < NS; ++s) {
        __syncthreads();  // drains this wave's DMA (vmcnt) + syncs buffers
        if (s + 1 < NS) {
#pragma unroll
            for (int i = 0; i < 6; ++i)
                GLD16(g[i] + (size_t)(s + 1) * KS, &xs[(s + 1) & 1][lo[i]]);
        }
        const float* xa = &xs[s & 1][tid * KS];          // token t0+tid
        const float* xb = &xs[s & 1][(tid + 256) * KS];  // token t0+tid+256
        const int kb = k0 + s * KS;
#pragma unroll
        for (int kk = 0; kk < 3; ++kk) {
            float4 va = *(const float4*)&xa[kk * 4];  // stride 12 dw (R2: 0 conflicts @ same class)
            float4 vb = *(const float4*)&xb[kk * 4];
#pragma unroll
            for (int c = 0; c < 4; ++c) {
                float fa = (&va.x)[c], fb = (&vb.x)[c];
                int kg = kb + kk * 4 + c;  // wave-uniform -> s_load_dwordx16
                vf16 w0 = wtv[kg * 2 + 0];
                vf16 w1 = wtv[kg * 2 + 1];
#pragma unroll
                for (int e = 0; e < 16; ++e) {
                    acc[e]      += fa * w0[e];
                    acc[16 + e] += fa * w1[e];
                    acc[32 + e] += fb * w0[e];
                    acc[48 + e] += fb * w1[e];
                }
            }
        }
    }

    float4* oa = (float4*)(part + ((size_t)blockIdx.y * T + t0 + tid) * E_NUM);
    float4* ob = (float4*)(part + ((size_t)blockIdx.y * T + t0 + tid + 256) * E_NUM);
#pragma unroll
    for (int j = 0; j < 8; ++j) {
        oa[j] = make_float4(acc[j * 4], acc[j * 4 + 1], acc[j * 4 + 2], acc[j * 4 + 3]);
        ob[j] = make_float4(acc[32 + j * 4], acc[32 + j * 4 + 1],
                            acc[32 + j * 4 + 2], acc[32 + j * 4 + 3]);
    }
}

// ---------------- Kernel C: reduce 16 chunks + bias, top-4, softmax ----------------
// block 256 = 64 tokens x 4 waves; wave g sums chunks 4g..4g+3; LDS reduce; wave 0
// does top-k+softmax. 4x the load parallelism of the old 64-thread version.
__global__ __launch_bounds__(256) void topk_softmax(
    const float* __restrict__ part, const float* __restrict__ bias,
    float* __restrict__ out, int T) {
    __shared__ float red[3][64][36];  // pad 32->36: conflict-safe stride
    const int tid = threadIdx.x, g = tid >> 6, l = tid & 63;
    const int t = blockIdx.x * 64 + l;

    float s[E_NUM];
#pragma unroll
    for (int e = 0; e < E_NUM; ++e) s[e] = 0.f;
#pragma unroll
    for (int q = 0; q < 4; ++q) {
        const int hc = g * 4 + q;
        const float4* p4 = (const float4*)(part + ((size_t)hc * T + t) * E_NUM);
#pragma unroll
        for (int j = 0; j < 8; ++j) {
            float4 p = p4[j];
            s[j * 4] += p.x; s[j * 4 + 1] += p.y;
            s[j * 4 + 2] += p.z; s[j * 4 + 3] += p.w;
        }
    }
    if (g > 0) {
#pragma unroll
        for (int j = 0; j < 8; ++j)
            *(float4*)&red[g - 1][l][j * 4] =
                make_float4(s[j * 4], s[j * 4 + 1], s[j * 4 + 2], s[j * 4 + 3]);
    }
    __syncthreads();
    if (g == 0) {
        float logit[E_NUM];
        const float4* b4 = (const float4*)bias;
#pragma unroll
        for (int j = 0; j < 8; ++j) {
            float4 b = b4[j];
            logit[j * 4] = b.x; logit[j * 4 + 1] = b.y;
            logit[j * 4 + 2] = b.z; logit[j * 4 + 3] = b.w;
        }
#pragma unroll
        for (int e = 0; e < E_NUM; ++e)
            logit[e] += s[e] + red[0][l][e] + red[1][l][e] + red[2][l][e];

        // top-4 descending, ties -> lowest index
        int idx[TOPK];
        float val[TOPK];
#pragma unroll
        for (int k = 0; k < TOPK; ++k) {
            float best = -INFINITY;
            int bi = 0;
#pragma unroll
            for (int e = 0; e < E_NUM; ++e) {
                bool taken = false;
                for (int p = 0; p < k; ++p) taken = taken || (idx[p] == e);
                float v = logit[e];
                if (!taken && v > best) { best = v; bi = e; }
            }
            idx[k] = bi;
            val[k] = best;
        }
        float ex[TOPK], sum = 0.f;
#pragma unroll
        for (int k = 0; k < TOPK; ++k) { ex[k] = expf(val[k] - val[0]); sum += ex[k]; }
        float inv = 1.f / sum;
#pragma unroll
        for (int k = 0; k < TOPK; ++k) {
            out[(size_t)t * 4 + k] = (float)idx[k];
            out[(size_t)T * 4 + (size_t)t * 4 + k] = ex[k] * inv;
        }
    }
}

extern "C" void kernel_launch(void* const* d_in, const int* in_sizes, int n_in,
                              void* d_out, int out_size, void* d_ws, size_t ws_size,
                              hipStream_t stream) {
    const float* x    = (const float*)d_in[0];  // [B,S,H] fp32
    const float* w    = (const float*)d_in[1];  // [E,H] fp32
    const float* bias = (const float*)d_in[2];  // [E] fp32
    float* out = (float*)d_out;

    const int T = in_sizes[0] / H_DIM;  // 16384

    float* part = (float*)d_ws;                    // [NCH][T][E] = 33.5 MB
    float* wt = part + (size_t)NCH * T * E_NUM;    // [H][E], 64B-aligned offset

    transpose_w<<<dim3(H_DIM / 32), dim3(32, 32), 0, stream>>>(w, wt);
    partial_logits<<<dim3(T / TB, NCH), 256, 0, stream>>>(x, wt, part, T);
    topk_softmax<<<dim3(T / 64), 256, 0, stream>>>(part, bias, out, T);
}